// Round 7
// baseline (94.836 us; speedup 1.0000x reference)
//
#include <hip/hip_runtime.h>

typedef __attribute__((ext_vector_type(8))) short bf16x8;
typedef __attribute__((ext_vector_type(4))) float f32x4;
typedef unsigned int u32;

#define TOK 16384
#define DIM 128
#define SEQ 2048

__device__ inline unsigned short f2bf(float f){
  union { float f; u32 u; } v; v.f = f;
  u32 r = v.u + 0x7fffu + ((v.u >> 16) & 1u);
  return (unsigned short)(r >> 16);
}
__device__ inline float bf2f(unsigned short u){
  union { u32 u; float f; } v; v.u = ((u32)u) << 16;
  return v.f;
}

__device__ inline void gld16(const void* g, const void* l){
  __builtin_amdgcn_global_load_lds((const __attribute__((address_space(1))) void*)g,
                                   (__attribute__((address_space(3))) void*)l, 16, 0, 0);
}

template<int CTRL>
__device__ inline float dppf(float x){
  return __builtin_bit_cast(float,
    __builtin_amdgcn_update_dpp(0, __builtin_bit_cast(int, x), CTRL, 0xF, 0xF, true));
}
__device__ inline float rmax16(float x){
  x = fmaxf(x, dppf<0xB1>(x));
  x = fmaxf(x, dppf<0x4E>(x));
  x = fmaxf(x, dppf<0x124>(x));
  x = fmaxf(x, dppf<0x128>(x));
  return x;
}
__device__ inline float rsum16(float x){
  x += dppf<0xB1>(x);
  x += dppf<0x4E>(x);
  x += dppf<0x124>(x);
  x += dppf<0x128>(x);
  return x;
}

// counted-vmcnt barrier: leave N loads in flight across the barrier
#define BAR_VM(N) do{ __builtin_amdgcn_sched_barrier(0); \
  asm volatile("s_waitcnt vmcnt(" #N ")" ::: "memory"); \
  __builtin_amdgcn_sched_barrier(0); \
  __builtin_amdgcn_s_barrier(); \
  __builtin_amdgcn_sched_barrier(0); }while(0)

// ---------------- kernel 0: weights -> bf16, transposed [out][in], chunk-swizzled ----------------
__global__ __launch_bounds__(256) void prep_w(const float* __restrict__ W1, const float* __restrict__ Wq,
                                              const float* __restrict__ Wk, const float* __restrict__ Wv,
                                              unsigned short* __restrict__ wt){
  int w = blockIdx.x >> 2, qtr = blockIdx.x & 3;
  const float* W = (w==0)?W1:((w==1)?Wq:((w==2)?Wk:Wv));
  unsigned short* dst = wt + w*16384;
  int c = threadIdx.x & 127;
  int khalf = threadIdx.x >> 7;
  int kbase = qtr*32 + khalf*16;
  unsigned short tmp[16];
  #pragma unroll
  for (int i=0;i<16;i++) tmp[i] = f2bf(W[(kbase+i)*128 + c]);
  #pragma unroll
  for (int h=0;h<2;h++){
    int k0 = kbase + h*8;
    int chunk = (k0 >> 3) ^ (c & 7);
    bf16x8 pk;
    #pragma unroll
    for (int j=0;j<8;j++) pk[j] = (short)tmp[h*8+j];
    *reinterpret_cast<bf16x8*>(dst + c*128 + chunk*8) = pk;
  }
}

// ---------------- kernel 1: res = q@W1 ; qh/kh/vh = res@{Wq,Wk,Wv}  (512 thr, 8 waves) ----------------
__global__ __launch_bounds__(512,2) void proj(const float* __restrict__ q, const unsigned short* __restrict__ wt,
                                              float* __restrict__ out,
                                              unsigned short* __restrict__ qh, unsigned short* __restrict__ khsw,
                                              unsigned short* __restrict__ vht){
  __shared__ unsigned short sW[4*128*128];   // 128 KB
  __shared__ unsigned short sX[64*128];      // 16 KB
  unsigned short* sVh = sW;                  // alias W1 region (dead after GEMM1)

  int tid = threadIdx.x;
  int lane = tid & 63, wid = tid >> 6;       // 8 waves
  int l15 = lane & 15, lg = lane >> 4;
  int wr = wid & 3;                          // row-wave: rows wr*16..+16
  int chh = wid >> 2;                        // col half: cols chh*64..+64
  int rowbase = blockIdx.x * 64;

  #pragma unroll
  for (int p=0;p<16;p++)
    gld16((const char*)wt + p*8192 + tid*16, (const char*)sW + p*8192 + wid*1024);

  { // q tile -> bf16, chunk-swizzled rows
    int r = tid >> 3, cg = tid & 7;
    const float* qp = q + (size_t)(rowbase + r)*128 + cg*16;
    #pragma unroll
    for (int c8=0;c8<2;c8++){
      bf16x8 pk;
      #pragma unroll
      for (int j=0;j<8;j++) pk[j] = (short)f2bf(qp[c8*8 + j]);
      int chunk = (cg*2 + c8) ^ (r & 7);
      *reinterpret_cast<bf16x8*>(sX + r*128 + chunk*8) = pk;
    }
  }
  __syncthreads();

  auto gemm = [&](const unsigned short* sA, const unsigned short* sB, f32x4 acc[4]){
    #pragma unroll
    for (int ct=0;ct<4;ct++) acc[ct] = (f32x4){0.f,0.f,0.f,0.f};
    #pragma unroll
    for (int kt=0;kt<4;kt++){
      int ar = wr*16 + l15;
      bf16x8 a = *reinterpret_cast<const bf16x8*>(sA + ar*128 + (((kt*4+lg) ^ (ar&7))*8));
      #pragma unroll
      for (int ct=0;ct<4;ct++){
        int cc = chh*64 + ct*16 + l15;
        bf16x8 bb = *reinterpret_cast<const bf16x8*>(sB + cc*128 + (((kt*4+lg) ^ (cc&7))*8));
        acc[ct] = __builtin_amdgcn_mfma_f32_16x16x32_bf16(a, bb, acc[ct], 0, 0, 0);
      }
    }
  };

  f32x4 acc[4];

  // GEMM1: res
  gemm(sX, sW, acc);
  #pragma unroll
  for (int ct=0;ct<4;ct++)
    #pragma unroll
    for (int i=0;i<4;i++){
      int r = wr*16 + lg*4 + i, c = chh*64 + ct*16 + l15;
      int rg = rowbase + r;
      float v = acc[ct][i];
      out[rg*256 + 128 + c] = v;
      out[TOK*256 + rg*128 + c] = v;
    }
  __syncthreads();
  #pragma unroll
  for (int ct=0;ct<4;ct++)
    #pragma unroll
    for (int i=0;i<4;i++){
      int r = wr*16 + lg*4 + i, c = chh*64 + ct*16 + l15;
      sX[r*128 + (((c>>3) ^ (r&7))*8) + (c&7)] = f2bf(acc[ct][i]);
    }
  __syncthreads();

  // GEMM2: qh, fold (1/sqrt(128)) * log2(e)
  gemm(sX, sW + 16384, acc);
  const float SCALE = 0.12751742f;
  #pragma unroll
  for (int ct=0;ct<4;ct++)
    #pragma unroll
    for (int i=0;i<4;i++){
      int r = wr*16 + lg*4 + i, c = chh*64 + ct*16 + l15;
      qh[(rowbase + r)*128 + c] = f2bf(acc[ct][i]*SCALE);
    }

  // GEMM3: kh, row-chunk-swizzled
  gemm(sX, sW + 2*16384, acc);
  #pragma unroll
  for (int ct=0;ct<4;ct++)
    #pragma unroll
    for (int i=0;i<4;i++){
      int r = wr*16 + lg*4 + i, c = chh*64 + ct*16 + l15;
      int rg = rowbase + r;
      khsw[rg*128 + (c ^ ((rg&7)<<3))] = f2bf(acc[ct][i]);
    }

  // GEMM4: vh -> transposed [b][feat][n]
  gemm(sX, sW + 3*16384, acc);
  __syncthreads();
  #pragma unroll
  for (int ct=0;ct<4;ct++)
    #pragma unroll
    for (int i=0;i<4;i++){
      int r = wr*16 + lg*4 + i, c = chh*64 + ct*16 + l15;
      sVh[r*130 + c] = f2bf(acc[ct][i]);
    }
  __syncthreads();
  {
    int bb = rowbase >> 11;
    int n0 = rowbase & 2047;
    #pragma unroll
    for (int it=0; it<2; ++it){
      int idx = tid + it*512;
      int f = idx >> 3, ch = idx & 7;
      bf16x8 pk;
      #pragma unroll
      for (int j=0;j<8;j++) pk[j] = (short)sVh[(ch*8+j)*130 + f];
      int ci = (n0 >> 3) + ch;
      *reinterpret_cast<bf16x8*>(vht + bb*(DIM*SEQ) + f*SEQ + ci*8) = pk;
    }
  }
}

// ---------------- kernel 2: flash attention, split-KV x4, counted-vmcnt raw barriers ----------------
__global__ __launch_bounds__(256,3) void attn(const unsigned short* __restrict__ qh,
                                              const unsigned short* __restrict__ khsw,
                                              const unsigned short* __restrict__ vht,
                                              const float* __restrict__ adj,
                                              unsigned short* __restrict__ po,
                                              float* __restrict__ pml){
  __shared__ unsigned short sK[2][32*128];   // 8 KB each
  __shared__ unsigned short sV[2][128*32];   // 8 KB each
  __shared__ unsigned short sP[4][16*40];    // 5 KB total

  const int tid = threadIdx.x;
  const int lane = tid & 63, wid = tid >> 6;
  const int l15 = lane & 15, lg = lane >> 4;
  const int bfid = blockIdx.x;
  const int quarter = bfid >> 8;             // 0..3
  const int rest = bfid & 255;
  const int b = rest & 7, qblk = rest >> 3;  // bfid%8 == b -> per-batch XCD affinity
  const int qbase = qblk * 64;
  const int tokbase = b*SEQ + qbase;
  const int kvbase = quarter * 512;          // 16 tiles of 32
  const unsigned short* vhb = vht + (size_t)b*DIM*SEQ;
  const float* adjl = adj + ((size_t)b*SEQ + qbase + wid*16 + lg*4)*SEQ + kvbase + l15;

  bf16x8 qf[4];
  {
    const unsigned short* qp = qh + (size_t)(tokbase + wid*16 + l15)*128;
    #pragma unroll
    for (int kt=0;kt<4;kt++) qf[kt] = *reinterpret_cast<const bf16x8*>(qp + kt*32 + lg*8);
  }

  f32x4 o[8];
  #pragma unroll
  for (int ct=0;ct<8;ct++) o[ct] = (f32x4){0.f,0.f,0.f,0.f};
  float mrow[4], lrow[4];
  #pragma unroll
  for (int i=0;i<4;i++){ mrow[i] = -3e38f; lrow[i] = 0.f; }

  // issue order inside a tile: stage (4 gld16) FIRST, then adj (8 loads) —
  // so vmcnt(8) at the barrier retires K/V but leaves adj in flight.
  auto stage = [&](int tt){
    int db = tt & 1;
    const char* kb = (const char*)(khsw + (size_t)(b*SEQ + kvbase + tt*32)*128);
    #pragma unroll
    for (int p=0;p<2;p++)
      gld16(kb + p*4096 + tid*16, (const char*)sK[db] + p*4096 + wid*1024);
    #pragma unroll
    for (int p=0;p<2;p++){
      int u = p*256 + tid;
      int ff = u >> 2, cp = u & 3;
      gld16(vhb + (size_t)ff*SEQ + kvbase + tt*32 + ((cp ^ (ff&3))*8),
            (const char*)sV[db] + p*4096 + wid*1024);
    }
  };
  auto ldadj = [&](int tt, float* a){
    const float* ap = adjl + tt*32;
    #pragma unroll
    for (int i=0;i<4;i++)
      #pragma unroll
      for (int ct=0;ct<2;ct++)
        a[i*2+ct] = __builtin_nontemporal_load(ap + (size_t)i*SEQ + ct*16);
  };

  // one tile: af = mask regs for tile t (consumed at top); optionally issue
  // stage(t+1) and adj(adjt) into afre (same array as af — WAR is safe,
  // reads precede the reload in program order).
  auto body = [&](int t, float* af, float* afre, int adjt, bool dostage, bool doadj){
    const int db = t & 1;
    const unsigned short* K = sK[db];
    const unsigned short* V = sV[db];

    // consume mask first: the compiler's auto-wait for af lands HERE,
    // before any new loads are issued this tile.
    float msel[8];
    #pragma unroll
    for (int j=0;j<8;j++) msel[j] = (af[j]==0.f) ? -1e9f : 0.f;

    if (dostage) stage(t+1);
    if (doadj)  ldadj(adjt, afre);

    // S = Q K^T : 16 rows x 32 kv
    f32x4 s[2];
    #pragma unroll
    for (int ct=0;ct<2;ct++) s[ct] = (f32x4){0.f,0.f,0.f,0.f};
    #pragma unroll
    for (int kt=0;kt<4;kt++){
      #pragma unroll
      for (int ct=0;ct<2;ct++){
        int kr = ct*16 + l15;
        bf16x8 kf = *reinterpret_cast<const bf16x8*>(K + kr*128 + (((kt*4+lg) ^ (kr&7))*8));
        s[ct] = __builtin_amdgcn_mfma_f32_16x16x32_bf16(qf[kt], kf, s[ct], 0,0,0);
      }
    }
    // mask as addend (exp2 of ~-1e9 flushes to 0 exactly, same as reference)
    #pragma unroll
    for (int i=0;i<4;i++)
      #pragma unroll
      for (int ct=0;ct<2;ct++)
        s[ct][i] += msel[i*2+ct];

    // online softmax (exp2 domain), defer-max THR=8
    #pragma unroll
    for (int i=0;i<4;i++){
      float pm = fmaxf(s[0][i], s[1][i]);
      pm = rmax16(pm);
      if (__any(pm > mrow[i] + 8.f)){
        float nm = fmaxf(mrow[i], pm);
        float scv = exp2f(mrow[i] - nm);
        mrow[i] = nm;
        lrow[i] *= scv;
        #pragma unroll
        for (int ct=0;ct<8;ct++) o[ct][i] *= scv;
      }
      float p0 = exp2f(s[0][i] - mrow[i]);
      float p1 = exp2f(s[1][i] - mrow[i]);
      s[0][i]=p0; s[1][i]=p1;
      lrow[i] += rsum16(p0+p1);
    }
    // P -> per-wave LDS (C-layout -> A-layout)
    unsigned short* Pw = sP[wid];
    #pragma unroll
    for (int ct=0;ct<2;ct++)
      #pragma unroll
      for (int i=0;i<4;i++)
        Pw[(lg*4+i)*40 + ct*16 + l15] = f2bf(s[ct][i]);
    bf16x8 pa = *reinterpret_cast<const bf16x8*>(Pw + l15*40 + lg*8);
    // O += P V
    #pragma unroll
    for (int ct=0;ct<8;ct++){
      int ff = ct*16 + l15;
      bf16x8 vf = *reinterpret_cast<const bf16x8*>(V + ff*32 + ((lg ^ (ff&3))*8));
      o[ct] = __builtin_amdgcn_mfma_f32_16x16x32_bf16(pa, vf, o[ct], 0,0,0);
    }
  };

  float afA[8], afB[8];

  // prologue: stage(0) first, then adj(0), adj(1); retire only stage(0).
  stage(0);
  ldadj(0, afA);
  ldadj(1, afB);
  BAR_VM(16);

  // steady state: tiles 0..13, vmcnt(8) leaves the 8 adj loads in flight
  #pragma unroll 1
  for (int t=0; t<14; t+=2){
    body(t,   afA, afA, t+2, true, true);   // stage(t+1), adj(t+2)->afA
    BAR_VM(8);
    body(t+1, afB, afB, t+3, true, true);   // stage(t+2), adj(t+3)->afB
    BAR_VM(8);
  }
  // peel tiles 14, 15
  body(14, afA, afA, 0, true, false);       // stage(15), no adj
  BAR_VM(0);
  body(15, afB, afB, 0, false, false);      // final tile, no barrier

  // write unnormalized partials + (m,l)
  #pragma unroll
  for (int ct=0;ct<8;ct++)
    #pragma unroll
    for (int i=0;i<4;i++){
      int row = tokbase + wid*16 + lg*4 + i;
      po[(size_t)(quarter*TOK + row)*128 + ct*16 + l15] = f2bf(o[ct][i]);
    }
  if (l15 == 0){
    #pragma unroll
    for (int i=0;i<4;i++){
      int row = tokbase + wid*16 + lg*4 + i;
      pml[(size_t)row*8 + quarter*2 + 0] = mrow[i];
      pml[(size_t)row*8 + quarter*2 + 1] = lrow[i];
    }
  }
}

// ---------------- kernel 3: merge 4 split-KV partials ----------------
__global__ __launch_bounds__(256) void merge(const unsigned short* __restrict__ po,
                                             const float* __restrict__ pml,
                                             float* __restrict__ out){
  const int mblk = blockIdx.x;
  const int b = mblk & 7, qblk = mblk >> 3;  // same XCD as producers
  const int tokbase = b*SEQ + qblk*64;
  const int tid = threadIdx.x;
  const int row = tokbase + (tid >> 2);
  const int c0 = (tid & 3) * 32;

  f32x4 ml0 = *reinterpret_cast<const f32x4*>(pml + (size_t)row*8);
  f32x4 ml1 = *reinterpret_cast<const f32x4*>(pml + (size_t)row*8 + 4);
  float m[4] = {ml0[0], ml0[2], ml1[0], ml1[2]};
  float l[4] = {ml0[1], ml0[3], ml1[1], ml1[3]};
  float M = fmaxf(fmaxf(m[0], m[1]), fmaxf(m[2], m[3]));
  float a[4], L = 0.f;
  #pragma unroll
  for (int qq=0;qq<4;qq++){ a[qq] = exp2f(m[qq] - M); L += a[qq]*l[qq]; }
  float inv = 1.f / L;
  #pragma unroll
  for (int qq=0;qq<4;qq++) a[qq] *= inv;

  float* op = out + (size_t)row*256 + c0;
  #pragma unroll
  for (int k=0;k<4;k++){
    float r[8];
    #pragma unroll
    for (int j=0;j<8;j++) r[j] = 0.f;
    #pragma unroll
    for (int qq=0;qq<4;qq++){
      bf16x8 v = *reinterpret_cast<const bf16x8*>(po + (size_t)(qq*TOK + row)*128 + c0 + k*8);
      #pragma unroll
      for (int j=0;j<8;j++) r[j] += bf2f((unsigned short)v[j]) * a[qq];
    }
    float4 r0 = {r[0], r[1], r[2], r[3]};
    float4 r1 = {r[4], r[5], r[6], r[7]};
    *reinterpret_cast<float4*>(op + k*8)     = r0;
    *reinterpret_cast<float4*>(op + k*8 + 4) = r1;
  }
}

extern "C" void kernel_launch(void* const* d_in, const int* in_sizes, int n_in,
                              void* d_out, int out_size, void* d_ws, size_t ws_size,
                              hipStream_t stream){
  (void)in_sizes; (void)n_in; (void)out_size; (void)ws_size;
  const float* q   = (const float*)d_in[0];
  const float* adj = (const float*)d_in[3];
  const float* W1  = (const float*)d_in[4];
  const float* Wq  = (const float*)d_in[5];
  const float* Wk  = (const float*)d_in[6];
  const float* Wv  = (const float*)d_in[7];
  float* out = (float*)d_out;

  unsigned short* qh = (unsigned short*)d_ws;        // 4 MB
  unsigned short* kh = qh + (size_t)TOK*DIM;         // 4 MB
  unsigned short* vh = kh + (size_t)TOK*DIM;         // 4 MB
  unsigned short* wt = vh + (size_t)TOK*DIM;         // 128 KB
  unsigned short* po = wt + 4*128*128;               // 16.8 MB (4 x bf16 partial O)
  float*          pml = (float*)(po + (size_t)4*TOK*DIM);  // 512 KB

  prep_w<<<16,   256, 0, stream>>>(W1, Wq, Wk, Wv, wt);
  proj  <<<256,  512, 0, stream>>>(q, wt, out, qh, kh, vh);
  attn  <<<1024, 256, 0, stream>>>(qh, kh, vh, adj, po, pml);
  merge <<<256,  256, 0, stream>>>(po, pml, out);
}

// Round 8
// 83.646 us; speedup vs baseline: 1.1338x; 1.1338x over previous
//
#include <hip/hip_runtime.h>

typedef __attribute__((ext_vector_type(8))) short bf16x8;
typedef __attribute__((ext_vector_type(4))) float f32x4;
typedef unsigned int u32;

#define TOK 16384
#define DIM 128
#define SEQ 2048

__device__ inline unsigned short f2bf(float f){
  union { float f; u32 u; } v; v.f = f;
  u32 r = v.u + 0x7fffu + ((v.u >> 16) & 1u);
  return (unsigned short)(r >> 16);
}
__device__ inline float bf2f(unsigned short u){
  union { u32 u; float f; } v; v.u = ((u32)u) << 16;
  return v.f;
}

__device__ inline void gld16(const void* g, const void* l){
  __builtin_amdgcn_global_load_lds((const __attribute__((address_space(1))) void*)g,
                                   (__attribute__((address_space(3))) void*)l, 16, 0, 0);
}

template<int CTRL>
__device__ inline float dppf(float x){
  return __builtin_bit_cast(float,
    __builtin_amdgcn_update_dpp(0, __builtin_bit_cast(int, x), CTRL, 0xF, 0xF, true));
}
__device__ inline float rmax16(float x){
  x = fmaxf(x, dppf<0xB1>(x));
  x = fmaxf(x, dppf<0x4E>(x));
  x = fmaxf(x, dppf<0x124>(x));
  x = fmaxf(x, dppf<0x128>(x));
  return x;
}
__device__ inline float rsum16(float x){
  x += dppf<0xB1>(x);
  x += dppf<0x4E>(x);
  x += dppf<0x124>(x);
  x += dppf<0x128>(x);
  return x;
}

// counted-vmcnt barrier: retire staged K/V, leave adj loads in flight
#define BAR_VM(N) do{ asm volatile("s_waitcnt vmcnt(" #N ")" ::: "memory"); \
  __builtin_amdgcn_s_barrier(); }while(0)

// ---------------- kernel 0: weights -> bf16, transposed [out][in], chunk-swizzled ----------------
__global__ __launch_bounds__(256) void prep_w(const float* __restrict__ W1, const float* __restrict__ Wq,
                                              const float* __restrict__ Wk, const float* __restrict__ Wv,
                                              unsigned short* __restrict__ wt){
  int w = blockIdx.x >> 2, qtr = blockIdx.x & 3;
  const float* W = (w==0)?W1:((w==1)?Wq:((w==2)?Wk:Wv));
  unsigned short* dst = wt + w*16384;
  int c = threadIdx.x & 127;
  int khalf = threadIdx.x >> 7;
  int kbase = qtr*32 + khalf*16;
  unsigned short tmp[16];
  #pragma unroll
  for (int i=0;i<16;i++) tmp[i] = f2bf(W[(kbase+i)*128 + c]);
  #pragma unroll
  for (int h=0;h<2;h++){
    int k0 = kbase + h*8;
    int chunk = (k0 >> 3) ^ (c & 7);
    bf16x8 pk;
    #pragma unroll
    for (int j=0;j<8;j++) pk[j] = (short)tmp[h*8+j];
    *reinterpret_cast<bf16x8*>(dst + c*128 + chunk*8) = pk;
  }
}

// ---------------- kernel 1: res = q@W1 ; qh/kh/vh = res@{Wq,Wk,Wv}  (512 thr, 8 waves) ----------------
__global__ __launch_bounds__(512,2) void proj(const float* __restrict__ q, const unsigned short* __restrict__ wt,
                                              float* __restrict__ out,
                                              unsigned short* __restrict__ qh, unsigned short* __restrict__ khsw,
                                              unsigned short* __restrict__ vht){
  __shared__ unsigned short sW[4*128*128];   // 128 KB
  __shared__ unsigned short sX[64*128];      // 16 KB
  unsigned short* sVh = sW;                  // alias W1 region (dead after GEMM1)

  int tid = threadIdx.x;
  int lane = tid & 63, wid = tid >> 6;       // 8 waves
  int l15 = lane & 15, lg = lane >> 4;
  int wr = wid & 3;                          // row-wave: rows wr*16..+16
  int chh = wid >> 2;                        // col half: cols chh*64..+64
  int rowbase = blockIdx.x * 64;

  #pragma unroll
  for (int p=0;p<16;p++)
    gld16((const char*)wt + p*8192 + tid*16, (const char*)sW + p*8192 + wid*1024);

  { // q tile -> bf16, chunk-swizzled rows
    int r = tid >> 3, cg = tid & 7;
    const float* qp = q + (size_t)(rowbase + r)*128 + cg*16;
    #pragma unroll
    for (int c8=0;c8<2;c8++){
      bf16x8 pk;
      #pragma unroll
      for (int j=0;j<8;j++) pk[j] = (short)f2bf(qp[c8*8 + j]);
      int chunk = (cg*2 + c8) ^ (r & 7);
      *reinterpret_cast<bf16x8*>(sX + r*128 + chunk*8) = pk;
    }
  }
  __syncthreads();

  auto gemm = [&](const unsigned short* sA, const unsigned short* sB, f32x4 acc[4]){
    #pragma unroll
    for (int ct=0;ct<4;ct++) acc[ct] = (f32x4){0.f,0.f,0.f,0.f};
    #pragma unroll
    for (int kt=0;kt<4;kt++){
      int ar = wr*16 + l15;
      bf16x8 a = *reinterpret_cast<const bf16x8*>(sA + ar*128 + (((kt*4+lg) ^ (ar&7))*8));
      #pragma unroll
      for (int ct=0;ct<4;ct++){
        int cc = chh*64 + ct*16 + l15;
        bf16x8 bb = *reinterpret_cast<const bf16x8*>(sB + cc*128 + (((kt*4+lg) ^ (cc&7))*8));
        acc[ct] = __builtin_amdgcn_mfma_f32_16x16x32_bf16(a, bb, acc[ct], 0, 0, 0);
      }
    }
  };

  f32x4 acc[4];

  // GEMM1: res
  gemm(sX, sW, acc);
  #pragma unroll
  for (int ct=0;ct<4;ct++)
    #pragma unroll
    for (int i=0;i<4;i++){
      int r = wr*16 + lg*4 + i, c = chh*64 + ct*16 + l15;
      int rg = rowbase + r;
      float v = acc[ct][i];
      out[rg*256 + 128 + c] = v;
      out[TOK*256 + rg*128 + c] = v;
    }
  __syncthreads();
  #pragma unroll
  for (int ct=0;ct<4;ct++)
    #pragma unroll
    for (int i=0;i<4;i++){
      int r = wr*16 + lg*4 + i, c = chh*64 + ct*16 + l15;
      sX[r*128 + (((c>>3) ^ (r&7))*8) + (c&7)] = f2bf(acc[ct][i]);
    }
  __syncthreads();

  // GEMM2: qh, fold (1/sqrt(128)) * log2(e)
  gemm(sX, sW + 16384, acc);
  const float SCALE = 0.12751742f;
  #pragma unroll
  for (int ct=0;ct<4;ct++)
    #pragma unroll
    for (int i=0;i<4;i++){
      int r = wr*16 + lg*4 + i, c = chh*64 + ct*16 + l15;
      qh[(rowbase + r)*128 + c] = f2bf(acc[ct][i]*SCALE);
    }

  // GEMM3: kh, row-chunk-swizzled
  gemm(sX, sW + 2*16384, acc);
  #pragma unroll
  for (int ct=0;ct<4;ct++)
    #pragma unroll
    for (int i=0;i<4;i++){
      int r = wr*16 + lg*4 + i, c = chh*64 + ct*16 + l15;
      int rg = rowbase + r;
      khsw[rg*128 + (c ^ ((rg&7)<<3))] = f2bf(acc[ct][i]);
    }

  // GEMM4: vh -> transposed [b][feat][n]
  gemm(sX, sW + 3*16384, acc);
  __syncthreads();
  #pragma unroll
  for (int ct=0;ct<4;ct++)
    #pragma unroll
    for (int i=0;i<4;i++){
      int r = wr*16 + lg*4 + i, c = chh*64 + ct*16 + l15;
      sVh[r*130 + c] = f2bf(acc[ct][i]);
    }
  __syncthreads();
  {
    int bb = rowbase >> 11;
    int n0 = rowbase & 2047;
    #pragma unroll
    for (int it=0; it<2; ++it){
      int idx = tid + it*512;
      int f = idx >> 3, ch = idx & 7;
      bf16x8 pk;
      #pragma unroll
      for (int j=0;j<8;j++) pk[j] = (short)sVh[(ch*8+j)*130 + f];
      int ci = (n0 >> 3) + ch;
      *reinterpret_cast<bf16x8*>(vht + bb*(DIM*SEQ) + f*SEQ + ci*8) = pk;
    }
  }
}

// ---------------- kernel 2: flash attention, split-KV x4, KVBLK=32, counted-vmcnt barrier ----------------
__global__ __launch_bounds__(256,4) void attn(const unsigned short* __restrict__ qh,
                                              const unsigned short* __restrict__ khsw,
                                              const unsigned short* __restrict__ vht,
                                              const float* __restrict__ adj,
                                              unsigned short* __restrict__ po,
                                              float* __restrict__ pml){
  __shared__ unsigned short sK[2][32*128];   // 8 KB each
  __shared__ unsigned short sV[2][128*32];   // 8 KB each
  __shared__ unsigned short sP[4][16*40];    // 5 KB total

  const int tid = threadIdx.x;
  const int lane = tid & 63, wid = tid >> 6;
  const int l15 = lane & 15, lg = lane >> 4;
  const int bfid = blockIdx.x;
  const int quarter = bfid >> 8;             // 0..3
  const int rest = bfid & 255;
  const int b = rest & 7, qblk = rest >> 3;  // bfid%8 == b -> per-batch XCD affinity
  const int qbase = qblk * 64;
  const int tokbase = b*SEQ + qbase;
  const int kvbase = quarter * 512;          // 16 tiles of 32
  const unsigned short* vhb = vht + (size_t)b*DIM*SEQ;
  const float* adjl = adj + ((size_t)b*SEQ + qbase + wid*16 + lg*4)*SEQ + kvbase + l15;

  bf16x8 qf[4];
  {
    const unsigned short* qp = qh + (size_t)(tokbase + wid*16 + l15)*128;
    #pragma unroll
    for (int kt=0;kt<4;kt++) qf[kt] = *reinterpret_cast<const bf16x8*>(qp + kt*32 + lg*8);
  }

  f32x4 o[8];
  #pragma unroll
  for (int ct=0;ct<8;ct++) o[ct] = (f32x4){0.f,0.f,0.f,0.f};
  float mrow[4], lrow[4];
  #pragma unroll
  for (int i=0;i<4;i++){ mrow[i] = -3e38f; lrow[i] = 0.f; }

  // K/V staged first, adj after -> vmcnt(8) at barrier retires K/V only
  auto stage = [&](int tt){
    int db = tt & 1;
    const char* kb = (const char*)(khsw + (size_t)(b*SEQ + kvbase + tt*32)*128);
    #pragma unroll
    for (int p=0;p<2;p++)
      gld16(kb + p*4096 + tid*16, (const char*)sK[db] + p*4096 + wid*1024);
    #pragma unroll
    for (int p=0;p<2;p++){
      int u = p*256 + tid;
      int ff = u >> 2, cp = u & 3;
      gld16(vhb + (size_t)ff*SEQ + kvbase + tt*32 + ((cp ^ ((ff>>1)&3))*8),
            (const char*)sV[db] + p*4096 + wid*1024);
    }
  };
  auto ldadj = [&](int tt, float* a){
    const float* ap = adjl + tt*32;
    #pragma unroll
    for (int i=0;i<4;i++)
      #pragma unroll
      for (int ct=0;ct<2;ct++)
        a[i*2+ct] = __builtin_nontemporal_load(ap + (size_t)i*SEQ + ct*16);
  };

  auto body = [&](int t, const float* a){
    const int db = t & 1;
    const unsigned short* K = sK[db];
    const unsigned short* V = sV[db];

    // S = Q K^T : 16 rows x 32 kv
    f32x4 s[2];
    #pragma unroll
    for (int ct=0;ct<2;ct++) s[ct] = (f32x4){0.f,0.f,0.f,0.f};
    #pragma unroll
    for (int kt=0;kt<4;kt++){
      #pragma unroll
      for (int ct=0;ct<2;ct++){
        int kr = ct*16 + l15;
        bf16x8 kf = *reinterpret_cast<const bf16x8*>(K + kr*128 + (((kt*4+lg) ^ (kr&7))*8));
        s[ct] = __builtin_amdgcn_mfma_f32_16x16x32_bf16(qf[kt], kf, s[ct], 0,0,0);
      }
    }
    // mask from registers (adj loads auto-waited here, mid-body)
    #pragma unroll
    for (int i=0;i<4;i++)
      #pragma unroll
      for (int ct=0;ct<2;ct++)
        if (a[i*2+ct] == 0.f) s[ct][i] = -1e9f;
    // online softmax (exp2 domain), defer-max THR=8
    #pragma unroll
    for (int i=0;i<4;i++){
      float pm = fmaxf(s[0][i], s[1][i]);
      pm = rmax16(pm);
      if (__any(pm > mrow[i] + 8.f)){
        float nm = fmaxf(mrow[i], pm);
        float scv = exp2f(mrow[i] - nm);
        mrow[i] = nm;
        lrow[i] *= scv;
        #pragma unroll
        for (int ct=0;ct<8;ct++) o[ct][i] *= scv;
      }
      float p0 = exp2f(s[0][i] - mrow[i]);
      float p1 = exp2f(s[1][i] - mrow[i]);
      s[0][i]=p0; s[1][i]=p1;
      lrow[i] += rsum16(p0+p1);
    }
    // P -> per-wave LDS (C-layout -> A-layout)
    unsigned short* Pw = sP[wid];
    #pragma unroll
    for (int ct=0;ct<2;ct++)
      #pragma unroll
      for (int i=0;i<4;i++)
        Pw[(lg*4+i)*40 + ct*16 + l15] = f2bf(s[ct][i]);
    bf16x8 pa = *reinterpret_cast<const bf16x8*>(Pw + l15*40 + lg*8);
    // O += P V
    #pragma unroll
    for (int ct=0;ct<8;ct++){
      int ff = ct*16 + l15;
      bf16x8 vf = *reinterpret_cast<const bf16x8*>(V + ff*32 + ((lg ^ ((ff>>1)&3))*8));
      o[ct] = __builtin_amdgcn_mfma_f32_16x16x32_bf16(pa, vf, o[ct], 0,0,0);
    }
  };

  float afA[8], afB[8];

  // prologue: stage(0) then adj(0); vmcnt(8) retires K/V only
  stage(0);
  ldadj(0, afA);
  BAR_VM(8);

  #pragma unroll 1
  for (int t=0; t<16; t+=2){
    if (t+1 < 16){ stage(t+1); ldadj(t+1, afB); }
    body(t, afA);
    BAR_VM(8);                     // stage(t+1) retired; adj(t+1) stays in flight
    if (t+2 < 16){ stage(t+2); ldadj(t+2, afA); }
    body(t+1, afB);
    if (t+2 < 16) BAR_VM(8);       // stage(t+2) retired; adj(t+2) stays in flight
  }

  // write unnormalized partials + (m,l)
  #pragma unroll
  for (int ct=0;ct<8;ct++)
    #pragma unroll
    for (int i=0;i<4;i++){
      int row = tokbase + wid*16 + lg*4 + i;
      po[(size_t)(quarter*TOK + row)*128 + ct*16 + l15] = f2bf(o[ct][i]);
    }
  if (l15 == 0){
    #pragma unroll
    for (int i=0;i<4;i++){
      int row = tokbase + wid*16 + lg*4 + i;
      pml[(size_t)row*8 + quarter*2 + 0] = mrow[i];
      pml[(size_t)row*8 + quarter*2 + 1] = lrow[i];
    }
  }
}

// ---------------- kernel 3: merge 4 split-KV partials ----------------
__global__ __launch_bounds__(256) void merge(const unsigned short* __restrict__ po,
                                             const float* __restrict__ pml,
                                             float* __restrict__ out){
  const int mblk = blockIdx.x;
  const int b = mblk & 7, qblk = mblk >> 3;  // same XCD as producers
  const int tokbase = b*SEQ + qblk*64;
  const int tid = threadIdx.x;
  const int row = tokbase + (tid >> 2);
  const int c0 = (tid & 3) * 32;

  f32x4 ml0 = *reinterpret_cast<const f32x4*>(pml + (size_t)row*8);
  f32x4 ml1 = *reinterpret_cast<const f32x4*>(pml + (size_t)row*8 + 4);
  float m[4] = {ml0[0], ml0[2], ml1[0], ml1[2]};
  float l[4] = {ml0[1], ml0[3], ml1[1], ml1[3]};
  float M = fmaxf(fmaxf(m[0], m[1]), fmaxf(m[2], m[3]));
  float a[4], L = 0.f;
  #pragma unroll
  for (int qq=0;qq<4;qq++){ a[qq] = exp2f(m[qq] - M); L += a[qq]*l[qq]; }
  float inv = 1.f / L;
  #pragma unroll
  for (int qq=0;qq<4;qq++) a[qq] *= inv;

  float* op = out + (size_t)row*256 + c0;
  #pragma unroll
  for (int k=0;k<4;k++){
    float r[8];
    #pragma unroll
    for (int j=0;j<8;j++) r[j] = 0.f;
    #pragma unroll
    for (int qq=0;qq<4;qq++){
      bf16x8 v = *reinterpret_cast<const bf16x8*>(po + (size_t)(qq*TOK + row)*128 + c0 + k*8);
      #pragma unroll
      for (int j=0;j<8;j++) r[j] += bf2f((unsigned short)v[j]) * a[qq];
    }
    float4 r0 = {r[0], r[1], r[2], r[3]};
    float4 r1 = {r[4], r[5], r[6], r[7]};
    *reinterpret_cast<float4*>(op + k*8)     = r0;
    *reinterpret_cast<float4*>(op + k*8 + 4) = r1;
  }
}

extern "C" void kernel_launch(void* const* d_in, const int* in_sizes, int n_in,
                              void* d_out, int out_size, void* d_ws, size_t ws_size,
                              hipStream_t stream){
  (void)in_sizes; (void)n_in; (void)out_size; (void)ws_size;
  const float* q   = (const float*)d_in[0];
  const float* adj = (const float*)d_in[3];
  const float* W1  = (const float*)d_in[4];
  const float* Wq  = (const float*)d_in[5];
  const float* Wk  = (const float*)d_in[6];
  const float* Wv  = (const float*)d_in[7];
  float* out = (float*)d_out;

  unsigned short* qh = (unsigned short*)d_ws;        // 4 MB
  unsigned short* kh = qh + (size_t)TOK*DIM;         // 4 MB
  unsigned short* vh = kh + (size_t)TOK*DIM;         // 4 MB
  unsigned short* wt = vh + (size_t)TOK*DIM;         // 128 KB
  unsigned short* po = wt + 4*128*128;               // 16.8 MB (4 x bf16 partial O)
  float*          pml = (float*)(po + (size_t)4*TOK*DIM);  // 512 KB

  prep_w<<<16,   256, 0, stream>>>(W1, Wq, Wk, Wv, wt);
  proj  <<<256,  512, 0, stream>>>(q, wt, out, qh, kh, vh);
  attn  <<<1024, 256, 0, stream>>>(qh, kh, vh, adj, po, pml);
  merge <<<256,  256, 0, stream>>>(po, pml, out);
}

// Round 9
// 80.136 us; speedup vs baseline: 1.1834x; 1.0438x over previous
//
#include <hip/hip_runtime.h>

typedef __attribute__((ext_vector_type(8))) short bf16x8;
typedef __attribute__((ext_vector_type(4))) float f32x4;
typedef unsigned int u32;

#define TOK 16384
#define DIM 128
#define SEQ 2048

__device__ inline unsigned short f2bf(float f){
  union { float f; u32 u; } v; v.f = f;
  u32 r = v.u + 0x7fffu + ((v.u >> 16) & 1u);
  return (unsigned short)(r >> 16);
}
__device__ inline float bf2f(unsigned short u){
  union { u32 u; float f; } v; v.u = ((u32)u) << 16;
  return v.f;
}

__device__ inline void gld16(const void* g, const void* l){
  __builtin_amdgcn_global_load_lds((const __attribute__((address_space(1))) void*)g,
                                   (__attribute__((address_space(3))) void*)l, 16, 0, 0);
}

template<int CTRL>
__device__ inline float dppf(float x){
  return __builtin_bit_cast(float,
    __builtin_amdgcn_update_dpp(0, __builtin_bit_cast(int, x), CTRL, 0xF, 0xF, true));
}
__device__ inline float rmax16(float x){
  x = fmaxf(x, dppf<0xB1>(x));
  x = fmaxf(x, dppf<0x4E>(x));
  x = fmaxf(x, dppf<0x124>(x));
  x = fmaxf(x, dppf<0x128>(x));
  return x;
}
__device__ inline float rsum16(float x){
  x += dppf<0xB1>(x);
  x += dppf<0x4E>(x);
  x += dppf<0x124>(x);
  x += dppf<0x128>(x);
  return x;
}

// counted-vmcnt barrier: retire staged K/V, leave adj loads in flight
#define BAR_VM(N) do{ asm volatile("s_waitcnt vmcnt(" #N ")" ::: "memory"); \
  __builtin_amdgcn_s_barrier(); }while(0)

// ---------------- kernel 0: weights -> bf16, transposed [out][in], chunk-swizzled ----------------
__global__ __launch_bounds__(256) void prep_w(const float* __restrict__ W1, const float* __restrict__ Wq,
                                              const float* __restrict__ Wk, const float* __restrict__ Wv,
                                              unsigned short* __restrict__ wt){
  int w = blockIdx.x >> 2, qtr = blockIdx.x & 3;
  const float* W = (w==0)?W1:((w==1)?Wq:((w==2)?Wk:Wv));
  unsigned short* dst = wt + w*16384;
  int c = threadIdx.x & 127;
  int khalf = threadIdx.x >> 7;
  int kbase = qtr*32 + khalf*16;
  unsigned short tmp[16];
  #pragma unroll
  for (int i=0;i<16;i++) tmp[i] = f2bf(W[(kbase+i)*128 + c]);
  #pragma unroll
  for (int h=0;h<2;h++){
    int k0 = kbase + h*8;
    int chunk = (k0 >> 3) ^ (c & 7);
    bf16x8 pk;
    #pragma unroll
    for (int j=0;j<8;j++) pk[j] = (short)tmp[h*8+j];
    *reinterpret_cast<bf16x8*>(dst + c*128 + chunk*8) = pk;
  }
}

// ---------------- kernel 1: res = q@W1 ; qh/kh/vh = res@{Wq,Wk,Wv}  (512 thr, 8 waves) ----------------
__global__ __launch_bounds__(512,2) void proj(const float* __restrict__ q, const unsigned short* __restrict__ wt,
                                              float* __restrict__ out,
                                              unsigned short* __restrict__ qh, unsigned short* __restrict__ khsw,
                                              unsigned short* __restrict__ vht){
  __shared__ unsigned short sW[4*128*128];   // 128 KB
  __shared__ unsigned short sX[64*128];      // 16 KB
  unsigned short* sVh = sW;                  // alias W1 region (dead after GEMM1)

  int tid = threadIdx.x;
  int lane = tid & 63, wid = tid >> 6;       // 8 waves
  int l15 = lane & 15, lg = lane >> 4;
  int wr = wid & 3;                          // row-wave: rows wr*16..+16
  int chh = wid >> 2;                        // col half: cols chh*64..+64
  int rowbase = blockIdx.x * 64;

  #pragma unroll
  for (int p=0;p<16;p++)
    gld16((const char*)wt + p*8192 + tid*16, (const char*)sW + p*8192 + wid*1024);

  { // q tile -> bf16, chunk-swizzled rows
    int r = tid >> 3, cg = tid & 7;
    const float* qp = q + (size_t)(rowbase + r)*128 + cg*16;
    #pragma unroll
    for (int c8=0;c8<2;c8++){
      bf16x8 pk;
      #pragma unroll
      for (int j=0;j<8;j++) pk[j] = (short)f2bf(qp[c8*8 + j]);
      int chunk = (cg*2 + c8) ^ (r & 7);
      *reinterpret_cast<bf16x8*>(sX + r*128 + chunk*8) = pk;
    }
  }
  __syncthreads();

  auto gemm = [&](const unsigned short* sA, const unsigned short* sB, f32x4 acc[4]){
    #pragma unroll
    for (int ct=0;ct<4;ct++) acc[ct] = (f32x4){0.f,0.f,0.f,0.f};
    #pragma unroll
    for (int kt=0;kt<4;kt++){
      int ar = wr*16 + l15;
      bf16x8 a = *reinterpret_cast<const bf16x8*>(sA + ar*128 + (((kt*4+lg) ^ (ar&7))*8));
      #pragma unroll
      for (int ct=0;ct<4;ct++){
        int cc = chh*64 + ct*16 + l15;
        bf16x8 bb = *reinterpret_cast<const bf16x8*>(sB + cc*128 + (((kt*4+lg) ^ (cc&7))*8));
        acc[ct] = __builtin_amdgcn_mfma_f32_16x16x32_bf16(a, bb, acc[ct], 0, 0, 0);
      }
    }
  };

  f32x4 acc[4];

  // GEMM1: res
  gemm(sX, sW, acc);
  #pragma unroll
  for (int ct=0;ct<4;ct++)
    #pragma unroll
    for (int i=0;i<4;i++){
      int r = wr*16 + lg*4 + i, c = chh*64 + ct*16 + l15;
      int rg = rowbase + r;
      float v = acc[ct][i];
      out[rg*256 + 128 + c] = v;
      out[TOK*256 + rg*128 + c] = v;
    }
  __syncthreads();
  #pragma unroll
  for (int ct=0;ct<4;ct++)
    #pragma unroll
    for (int i=0;i<4;i++){
      int r = wr*16 + lg*4 + i, c = chh*64 + ct*16 + l15;
      sX[r*128 + (((c>>3) ^ (r&7))*8) + (c&7)] = f2bf(acc[ct][i]);
    }
  __syncthreads();

  // GEMM2: qh, fold (1/sqrt(128)) * log2(e)
  gemm(sX, sW + 16384, acc);
  const float SCALE = 0.12751742f;
  #pragma unroll
  for (int ct=0;ct<4;ct++)
    #pragma unroll
    for (int i=0;i<4;i++){
      int r = wr*16 + lg*4 + i, c = chh*64 + ct*16 + l15;
      qh[(rowbase + r)*128 + c] = f2bf(acc[ct][i]*SCALE);
    }

  // GEMM3: kh, row-chunk-swizzled
  gemm(sX, sW + 2*16384, acc);
  #pragma unroll
  for (int ct=0;ct<4;ct++)
    #pragma unroll
    for (int i=0;i<4;i++){
      int r = wr*16 + lg*4 + i, c = chh*64 + ct*16 + l15;
      int rg = rowbase + r;
      khsw[rg*128 + (c ^ ((rg&7)<<3))] = f2bf(acc[ct][i]);
    }

  // GEMM4: vh -> transposed [b][feat][n]
  gemm(sX, sW + 3*16384, acc);
  __syncthreads();
  #pragma unroll
  for (int ct=0;ct<4;ct++)
    #pragma unroll
    for (int i=0;i<4;i++){
      int r = wr*16 + lg*4 + i, c = chh*64 + ct*16 + l15;
      sVh[r*130 + c] = f2bf(acc[ct][i]);
    }
  __syncthreads();
  {
    int bb = rowbase >> 11;
    int n0 = rowbase & 2047;
    #pragma unroll
    for (int it=0; it<2; ++it){
      int idx = tid + it*512;
      int f = idx >> 3, ch = idx & 7;
      bf16x8 pk;
      #pragma unroll
      for (int j=0;j<8;j++) pk[j] = (short)sVh[(ch*8+j)*130 + f];
      int ci = (n0 >> 3) + ch;
      *reinterpret_cast<bf16x8*>(vht + bb*(DIM*SEQ) + f*SEQ + ci*8) = pk;
    }
  }
}

// ---------------- kernel 2: flash attention, split-KV x4, 32 q-rows/wave (LDS-BW halved) ----------------
__global__ __launch_bounds__(256,2) void attn(const unsigned short* __restrict__ qh,
                                              const unsigned short* __restrict__ khsw,
                                              const unsigned short* __restrict__ vht,
                                              const float* __restrict__ adj,
                                              unsigned short* __restrict__ po,
                                              float* __restrict__ pml){
  __shared__ unsigned short sK[2][32*128];   // 8 KB each
  __shared__ unsigned short sV[2][128*32];   // 8 KB each
  __shared__ unsigned short sP[4][32*40];    // 10 KB total

  const int tid = threadIdx.x;
  const int lane = tid & 63, wid = tid >> 6;
  const int l15 = lane & 15, lg = lane >> 4;
  const int bfid = blockIdx.x;               // 512 = 4 quarters x 16 qblk x 8 batch
  const int quarter = bfid >> 7;             // 0..3
  const int b = bfid & 7;                    // batch -> XCD affinity
  const int qblk = (bfid >> 3) & 15;
  const int qbase = qblk * 128;              // block covers 128 q-rows
  const int tokbase = b*SEQ + qbase;
  const int kvbase = quarter * 512;          // 16 tiles of 32
  const int wrow = wid * 32;                 // wave's 32 rows within block
  const unsigned short* vhb = vht + (size_t)b*DIM*SEQ;
  const float* adjl = adj + ((size_t)b*SEQ + qbase + wrow + lg*4)*SEQ + kvbase + l15;

  // Q fragments: 2 row-subtiles x 4 k-tiles (scale+log2e pre-folded)
  bf16x8 qf[2][4];
  #pragma unroll
  for (int sub=0;sub<2;sub++){
    const unsigned short* qp = qh + (size_t)(tokbase + wrow + sub*16 + l15)*128;
    #pragma unroll
    for (int kt=0;kt<4;kt++) qf[sub][kt] = *reinterpret_cast<const bf16x8*>(qp + kt*32 + lg*8);
  }

  f32x4 o[2][8];
  #pragma unroll
  for (int sub=0;sub<2;sub++)
    #pragma unroll
    for (int ct=0;ct<8;ct++) o[sub][ct] = (f32x4){0.f,0.f,0.f,0.f};
  float mrow[2][4], lrow[2][4];
  #pragma unroll
  for (int sub=0;sub<2;sub++)
    #pragma unroll
    for (int i=0;i<4;i++){ mrow[sub][i] = -3e38f; lrow[sub][i] = 0.f; }

  // K/V staged first, adj after -> vmcnt(16) at barrier retires K/V only
  auto stage = [&](int tt){
    int db = tt & 1;
    const char* kb = (const char*)(khsw + (size_t)(b*SEQ + kvbase + tt*32)*128);
    #pragma unroll
    for (int p=0;p<2;p++)
      gld16(kb + p*4096 + tid*16, (const char*)sK[db] + p*4096 + wid*1024);
    #pragma unroll
    for (int p=0;p<2;p++){
      int u = p*256 + tid;
      int ff = u >> 2, cp = u & 3;
      gld16(vhb + (size_t)ff*SEQ + kvbase + tt*32 + ((cp ^ ((ff>>1)&3))*8),
            (const char*)sV[db] + p*4096 + wid*1024);
    }
  };
  auto ldadj = [&](int tt, float* a){
    const float* ap = adjl + tt*32;
    #pragma unroll
    for (int sub=0;sub<2;sub++)
      #pragma unroll
      for (int i=0;i<4;i++)
        #pragma unroll
        for (int ct=0;ct<2;ct++)
          a[sub*8+i*2+ct] = __builtin_nontemporal_load(ap + (size_t)(sub*16+i)*SEQ + ct*16);
  };

  auto body = [&](int t, const float* a){
    const int db = t & 1;
    const unsigned short* K = sK[db];
    const unsigned short* V = sV[db];

    // S = Q K^T : 32 rows x 32 kv ; K-frags read once, used by both subs
    f32x4 s[2][2];
    #pragma unroll
    for (int sub=0;sub<2;sub++)
      #pragma unroll
      for (int ct=0;ct<2;ct++) s[sub][ct] = (f32x4){0.f,0.f,0.f,0.f};
    #pragma unroll
    for (int kt=0;kt<4;kt++){
      #pragma unroll
      for (int ct=0;ct<2;ct++){
        int kr = ct*16 + l15;
        bf16x8 kf = *reinterpret_cast<const bf16x8*>(K + kr*128 + (((kt*4+lg) ^ (kr&7))*8));
        s[0][ct] = __builtin_amdgcn_mfma_f32_16x16x32_bf16(qf[0][kt], kf, s[0][ct], 0,0,0);
        s[1][ct] = __builtin_amdgcn_mfma_f32_16x16x32_bf16(qf[1][kt], kf, s[1][ct], 0,0,0);
      }
    }
    // mask from registers (adj loads auto-waited here, mid-body)
    #pragma unroll
    for (int sub=0;sub<2;sub++)
      #pragma unroll
      for (int i=0;i<4;i++)
        #pragma unroll
        for (int ct=0;ct<2;ct++)
          if (a[sub*8+i*2+ct] == 0.f) s[sub][ct][i] = -1e9f;
    // online softmax (exp2 domain), defer-max THR=8; 8 independent row-chains
    #pragma unroll
    for (int sub=0;sub<2;sub++)
      #pragma unroll
      for (int i=0;i<4;i++){
        float pm = fmaxf(s[sub][0][i], s[sub][1][i]);
        pm = rmax16(pm);
        if (__any(pm > mrow[sub][i] + 8.f)){
          float nm = fmaxf(mrow[sub][i], pm);
          float scv = exp2f(mrow[sub][i] - nm);
          mrow[sub][i] = nm;
          lrow[sub][i] *= scv;
          #pragma unroll
          for (int ct=0;ct<8;ct++) o[sub][ct][i] *= scv;
        }
        float p0 = exp2f(s[sub][0][i] - mrow[sub][i]);
        float p1 = exp2f(s[sub][1][i] - mrow[sub][i]);
        s[sub][0][i]=p0; s[sub][1][i]=p1;
        lrow[sub][i] += rsum16(p0+p1);
      }
    // P -> per-wave LDS (C-layout -> A-layout)
    unsigned short* Pw = sP[wid];
    #pragma unroll
    for (int sub=0;sub<2;sub++)
      #pragma unroll
      for (int ct=0;ct<2;ct++)
        #pragma unroll
        for (int i=0;i<4;i++)
          Pw[(sub*16+lg*4+i)*40 + ct*16 + l15] = f2bf(s[sub][ct][i]);
    bf16x8 pa[2];
    #pragma unroll
    for (int sub=0;sub<2;sub++)
      pa[sub] = *reinterpret_cast<const bf16x8*>(Pw + (sub*16+l15)*40 + lg*8);
    // O += P V ; V-frags read once, used by both subs
    #pragma unroll
    for (int ct=0;ct<8;ct++){
      int ff = ct*16 + l15;
      bf16x8 vf = *reinterpret_cast<const bf16x8*>(V + ff*32 + ((lg ^ ((ff>>1)&3))*8));
      o[0][ct] = __builtin_amdgcn_mfma_f32_16x16x32_bf16(pa[0], vf, o[0][ct], 0,0,0);
      o[1][ct] = __builtin_amdgcn_mfma_f32_16x16x32_bf16(pa[1], vf, o[1][ct], 0,0,0);
    }
  };

  float afA[16], afB[16];

  // prologue: stage(0) then adj(0); vmcnt(16) retires K/V only
  stage(0);
  ldadj(0, afA);
  BAR_VM(16);

  #pragma unroll 1
  for (int t=0; t<16; t+=2){
    if (t+1 < 16){ stage(t+1); ldadj(t+1, afB); }
    body(t, afA);
    BAR_VM(16);                    // stage(t+1) retired; adj(t+1) stays in flight
    if (t+2 < 16){ stage(t+2); ldadj(t+2, afA); }
    body(t+1, afB);
    if (t+2 < 16) BAR_VM(16);      // stage(t+2) retired; adj(t+2) stays in flight
  }

  // write unnormalized partials + (m,l)
  #pragma unroll
  for (int sub=0;sub<2;sub++)
    #pragma unroll
    for (int ct=0;ct<8;ct++)
      #pragma unroll
      for (int i=0;i<4;i++){
        int row = tokbase + wrow + sub*16 + lg*4 + i;
        po[(size_t)(quarter*TOK + row)*128 + ct*16 + l15] = f2bf(o[sub][ct][i]);
      }
  if (l15 == 0){
    #pragma unroll
    for (int sub=0;sub<2;sub++)
      #pragma unroll
      for (int i=0;i<4;i++){
        int row = tokbase + wrow + sub*16 + lg*4 + i;
        pml[(size_t)row*8 + quarter*2 + 0] = mrow[sub][i];
        pml[(size_t)row*8 + quarter*2 + 1] = lrow[sub][i];
      }
  }
}

// ---------------- kernel 3: merge 4 split-KV partials (512 blocks, 32 rows each) ----------------
__global__ __launch_bounds__(256) void merge(const unsigned short* __restrict__ po,
                                             const float* __restrict__ pml,
                                             float* __restrict__ out){
  const int mblk = blockIdx.x;               // 512 = 64 qblk x 8 batch
  const int b = mblk & 7, q32 = mblk >> 3;   // same XCD as producers
  const int tokbase = b*SEQ + q32*32;
  const int tid = threadIdx.x;
  const int row = tokbase + (tid >> 3);
  const int c0 = (tid & 7) * 16;

  f32x4 ml0 = *reinterpret_cast<const f32x4*>(pml + (size_t)row*8);
  f32x4 ml1 = *reinterpret_cast<const f32x4*>(pml + (size_t)row*8 + 4);
  float m[4] = {ml0[0], ml0[2], ml1[0], ml1[2]};
  float l[4] = {ml0[1], ml0[3], ml1[1], ml1[3]};
  float M = fmaxf(fmaxf(m[0], m[1]), fmaxf(m[2], m[3]));
  float a[4], L = 0.f;
  #pragma unroll
  for (int qq=0;qq<4;qq++){ a[qq] = exp2f(m[qq] - M); L += a[qq]*l[qq]; }
  float inv = 1.f / L;
  #pragma unroll
  for (int qq=0;qq<4;qq++) a[qq] *= inv;

  float r[16];
  #pragma unroll
  for (int j=0;j<16;j++) r[j] = 0.f;
  #pragma unroll
  for (int qq=0;qq<4;qq++){
    const unsigned short* pp = po + (size_t)(qq*TOK + row)*128 + c0;
    bf16x8 v0 = *reinterpret_cast<const bf16x8*>(pp);
    bf16x8 v1 = *reinterpret_cast<const bf16x8*>(pp + 8);
    #pragma unroll
    for (int j=0;j<8;j++){
      r[j]   += bf2f((unsigned short)v0[j]) * a[qq];
      r[8+j] += bf2f((unsigned short)v1[j]) * a[qq];
    }
  }
  float* op = out + (size_t)row*256 + c0;
  #pragma unroll
  for (int k=0;k<4;k++){
    float4 rv = {r[k*4+0], r[k*4+1], r[k*4+2], r[k*4+3]};
    *reinterpret_cast<float4*>(op + k*4) = rv;
  }
}

extern "C" void kernel_launch(void* const* d_in, const int* in_sizes, int n_in,
                              void* d_out, int out_size, void* d_ws, size_t ws_size,
                              hipStream_t stream){
  (void)in_sizes; (void)n_in; (void)out_size; (void)ws_size;
  const float* q   = (const float*)d_in[0];
  const float* adj = (const float*)d_in[3];
  const float* W1  = (const float*)d_in[4];
  const float* Wq  = (const float*)d_in[5];
  const float* Wk  = (const float*)d_in[6];
  const float* Wv  = (const float*)d_in[7];
  float* out = (float*)d_out;

  unsigned short* qh = (unsigned short*)d_ws;        // 4 MB
  unsigned short* kh = qh + (size_t)TOK*DIM;         // 4 MB
  unsigned short* vh = kh + (size_t)TOK*DIM;         // 4 MB
  unsigned short* wt = vh + (size_t)TOK*DIM;         // 128 KB
  unsigned short* po = wt + 4*128*128;               // 16.8 MB (4 x bf16 partial O)
  float*          pml = (float*)(po + (size_t)4*TOK*DIM);  // 512 KB

  prep_w<<<16,  256, 0, stream>>>(W1, Wq, Wk, Wv, wt);
  proj  <<<256, 512, 0, stream>>>(q, wt, out, qh, kh, vh);
  attn  <<<512, 256, 0, stream>>>(qh, kh, vh, adj, po, pml);
  merge <<<512, 256, 0, stream>>>(po, pml, out);
}